// Round 3
// baseline (247.314 us; speedup 1.0000x reference)
//
#include <hip/hip_runtime.h>

// Octree cross-entropy loss.
// D=256, BS=16 -> 4096 level-0 tiles of 16^3 voxels.
// Level 0: per-voxel 2-class CE, mean over tile, summed over tiles.
// Levels 1..4 (b = 32,64,128,256): 3-class CE (pure0/pure1/mixed) * b^3,
// class derived from per-16^3-tile popcounts of gt01 aggregated upward.
//
// R5 -> R6 changes:
//  - R3/R4/R5 (reg-prefetch x2 shapes, then global_load_lds + barrier) ALL
//    pinned at ~1650 GB/s / ~81 us: the invariant was 4096 short-lived
//    workgroups, each one tile + one full vmcnt(0) drain (~20 ns/block
//    dispatch rate, ~1 tile in flight per CU).
//  - R6: 512 persistent workgroups (2/CU, one dispatch round). Each wave
//    privately owns 2 tiles = 8 quarter-tiles, double-buffered DMA pipeline
//    with counted `s_waitcnt vmcnt(12)` (prefetch of quarter s+1 stays in
//    flight while computing quarter s). Wave-private LDS + wave-internal
//    reduction -> ZERO barriers, so the compiler never emits the
//    vmcnt(0)-before-s_barrier drain. Ping-pong buffers are distinct
//    __shared__ arrays so alias analysis yields precise counted waits.

__device__ __forceinline__ float softplus(float x) {
    // log(1 + e^x), stable
    return fmaxf(x, 0.f) + __logf(1.f + __expf(-fabsf(x)));
}

__device__ __forceinline__ float nll3(const float* __restrict__ l, int c) {
    float a = l[0], b = l[1], d = l[2];
    float m = fmaxf(fmaxf(a, b), d);
    float lse = m + __logf(__expf(a - m) + __expf(b - m) + __expf(d - m));
    return lse - l[c];
}

// HBM -> LDS direct DMA, 16 B per lane. Dest is wave-uniform base + lane*16.
#define GLOAD_LDS16(gsrc, ldst)                                                \
    __builtin_amdgcn_global_load_lds(                                          \
        (const __attribute__((address_space(1))) void*)(gsrc),                 \
        (__attribute__((address_space(3))) void*)(ldst), 16, 0, 0)

// 512 workgroups x 256 threads. Wave w of wg b owns tiles b*8+w*2, b*8+w*2+1,
// processed as 8 quarter-tiles (1024 voxels each) through a 2-deep pipeline.
__global__ __launch_bounds__(256, 2) void level0_kernel(
    const int* __restrict__ gt,        // [256^3], values +-1, x-major (x,y,z)
    const float* __restrict__ logits,  // [4096, 2, 4096]
    float* __restrict__ partial,       // [4096] per-tile mean NLL
    int* __restrict__ ones_count)      // [4096] per-tile popcount of gt01
{
    __shared__ float bufA[4][2048];    // per-wave ping: a-quarter | b-quarter
    __shared__ float bufB[4][2048];    // per-wave pong

    const int tid  = threadIdx.x;
    const int lane = tid & 63;
    const int wave = tid >> 6;
    const int t0   = blockIdx.x * 8 + wave * 2;   // first of 2 owned tiles

    float* const A = &bufA[wave][0];
    float* const B = &bufB[wave][0];

    // stage quarter s (0..7): tile t0+(s>>2), quarter q=s&3.
    // 8x 1KB DMA: a-floats [q*1024,+1024) then b-floats, linear in LDS.
    auto stage = [&](float* dst, int s) {
        const int tile = t0 + (s >> 2);
        const int q    = s & 3;
        const float* src = logits + (size_t)tile * 8192 + q * 1024;
#pragma unroll
        for (int c = 0; c < 4; ++c)
            GLOAD_LDS16(src + c * 256 + lane * 4, dst + c * 256);
#pragma unroll
        for (int c = 0; c < 4; ++c)
            GLOAD_LDS16(src + 4096 + c * 256 + lane * 4, dst + 1024 + c * 256);
    };
    // gt for quarter s: 4 int4 per lane. voxel v = q*1024 + j*256 + lane*4:
    // ix = q*4+j, iy = lane>>2, iz = (lane&3)*4.
    auto gtload = [&](int4* g, int s) {
        const int tile = t0 + (s >> 2);
        const int q    = s & 3;
        const int bx = tile >> 8, by = (tile >> 4) & 15, bz = tile & 15;
        const int base = (bx << 20) + (by << 12) + (bz << 4)
                       + ((lane >> 2) << 8) + ((lane & 3) << 2);
#pragma unroll
        for (int j = 0; j < 4; ++j)
            g[j] = *reinterpret_cast<const int4*>(gt + base + (((q << 2) + j) << 16));
    };

    int4 gcur[4], gnxt[4];
    stage(A, 0);
    gtload(gcur, 0);

    float lsum = 0.f;
    int   ones = 0;
#pragma unroll
    for (int s = 0; s < 8; ++s) {
        float* const cbuf = (s & 1) ? B : A;
        float* const nbuf = (s & 1) ? A : B;
        if (s < 7) {
            stage(nbuf, s + 1);          // 8 DMA ops
            gtload(gnxt, s + 1);         // 4 vector loads
            // wait for quarter s's 12 ops; keep quarter s+1's 12 in flight
            asm volatile("s_waitcnt vmcnt(12)" ::: "memory");
        } else {
            asm volatile("s_waitcnt vmcnt(0)" ::: "memory");
        }
        // per-voxel 2-class CE: tgt=1 -> softplus(l0-l1); 0 -> softplus(l1-l0)
#pragma unroll
        for (int j = 0; j < 4; ++j) {
            const float4 a = *reinterpret_cast<const float4*>(cbuf + j * 256 + lane * 4);
            const float4 b = *reinterpret_cast<const float4*>(cbuf + 1024 + j * 256 + lane * 4);
            const float dx = a.x - b.x;
            const float dy = a.y - b.y;
            const float dz = a.z - b.z;
            const float dw = a.w - b.w;
            const int t0c = gcur[j].x > 0, t1c = gcur[j].y > 0;
            const int t2c = gcur[j].z > 0, t3c = gcur[j].w > 0;
            ones += t0c + t1c + t2c + t3c;
            lsum += softplus(t0c ? dx : -dx)
                  + softplus(t1c ? dy : -dy)
                  + softplus(t2c ? dz : -dz)
                  + softplus(t3c ? dw : -dw);
        }
        if ((s & 3) == 3) {
            // finished a tile: wave-internal reduce, lane 0 writes out
            float ls = lsum;
            int   on = ones;
#pragma unroll
            for (int d = 32; d > 0; d >>= 1) {
                ls += __shfl_down(ls, d, 64);
                on += __shfl_down(on, d, 64);
            }
            if (lane == 0) {
                const int tile = t0 + (s >> 2);
                partial[tile]    = ls * (1.0f / 4096.0f);  // mean over 16^3
                ones_count[tile] = on;
            }
            lsum = 0.f;
            ones = 0;
        }
#pragma unroll
        for (int j = 0; j < 4; ++j) gcur[j] = gnxt[j];
    }
}

// Single block, 512 threads: reduce level-0 partials, hierarchical popcount
// aggregation, 3-class CE for levels 1..4, write final out[0].
__global__ __launch_bounds__(512) void levels_kernel(
    const float* __restrict__ partial, // [4096]
    const int* __restrict__ cnt0,      // [4096] ordered (bx*16+by)*16+bz
    const float* __restrict__ l1,      // [512,3]
    const float* __restrict__ l2,      // [64,3]
    const float* __restrict__ l3,      // [8,3]
    const float* __restrict__ l4,      // [1,3]
    float* __restrict__ out)
{
    __shared__ int   s1[512];
    __shared__ int   s2[64];
    __shared__ int   s3[8];
    __shared__ float red[512];
    const int tid = threadIdx.x;
    float contrib = 0.f;

    // level-0 partial losses: 8 floats per thread
    {
        const float4 p0 = *reinterpret_cast<const float4*>(partial + tid * 8);
        const float4 p1 = *reinterpret_cast<const float4*>(partial + tid * 8 + 4);
        contrib += (p0.x + p0.y + p0.z + p0.w) + (p1.x + p1.y + p1.z + p1.w);
    }

    // level 1: 8^3 blocks, each aggregates 2^3 level-0 tiles (16^3 grid)
    {
        const int X = tid >> 6, Y = (tid >> 3) & 7, Z = tid & 7;
        int s = 0;
#pragma unroll
        for (int dx = 0; dx < 2; ++dx)
#pragma unroll
            for (int dy = 0; dy < 2; ++dy)
#pragma unroll
                for (int dz = 0; dz < 2; ++dz)
                    s += cnt0[((X * 2 + dx) * 16 + (Y * 2 + dy)) * 16 + (Z * 2 + dz)];
        s1[tid] = s;
        const int tot = 8 * 4096;
        const int c = (s == 0) ? 0 : ((s == tot) ? 1 : 2);
        contrib += nll3(l1 + tid * 3, c) * 32768.0f;      // 32^3
    }
    __syncthreads();
    // level 2: 4^3 blocks from 8^3 grid
    if (tid < 64) {
        const int X = tid >> 4, Y = (tid >> 2) & 3, Z = tid & 3;
        int s = 0;
#pragma unroll
        for (int dx = 0; dx < 2; ++dx)
#pragma unroll
            for (int dy = 0; dy < 2; ++dy)
#pragma unroll
                for (int dz = 0; dz < 2; ++dz)
                    s += s1[((X * 2 + dx) * 8 + (Y * 2 + dy)) * 8 + (Z * 2 + dz)];
        s2[tid] = s;
        const int tot = 64 * 4096;
        const int c = (s == 0) ? 0 : ((s == tot) ? 1 : 2);
        contrib += nll3(l2 + tid * 3, c) * 262144.0f;     // 64^3
    }
    __syncthreads();
    // level 3: 2^3 blocks from 4^3 grid
    if (tid < 8) {
        const int X = tid >> 2, Y = (tid >> 1) & 1, Z = tid & 1;
        int s = 0;
#pragma unroll
        for (int dx = 0; dx < 2; ++dx)
#pragma unroll
            for (int dy = 0; dy < 2; ++dy)
#pragma unroll
                for (int dz = 0; dz < 2; ++dz)
                    s += s2[((X * 2 + dx) * 4 + (Y * 2 + dy)) * 4 + (Z * 2 + dz)];
        s3[tid] = s;
        const int tot = 512 * 4096;
        const int c = (s == 0) ? 0 : ((s == tot) ? 1 : 2);
        contrib += nll3(l3 + tid * 3, c) * 2097152.0f;    // 128^3
    }
    __syncthreads();
    // level 4: 1 block = everything
    if (tid == 0) {
        int s = 0;
#pragma unroll
        for (int i = 0; i < 8; ++i) s += s3[i];
        const int tot = 4096 * 4096;
        const int c = (s == 0) ? 0 : ((s == tot) ? 1 : 2);
        contrib += nll3(l4, c) * 16777216.0f;             // 256^3
    }

    red[tid] = contrib;
    __syncthreads();
#pragma unroll
    for (int s = 256; s > 0; s >>= 1) {
        if (tid < s) red[tid] += red[tid + s];
        __syncthreads();
    }
    if (tid == 0) out[0] = red[0];
}

extern "C" void kernel_launch(void* const* d_in, const int* in_sizes, int n_in,
                              void* d_out, int out_size, void* d_ws, size_t ws_size,
                              hipStream_t stream) {
    const int*   gt    = (const int*)d_in[0];
    const float* dense = (const float*)d_in[1];
    const float* l1    = (const float*)d_in[2];
    const float* l2    = (const float*)d_in[3];
    const float* l3    = (const float*)d_in[4];
    const float* l4    = (const float*)d_in[5];
    float* out = (float*)d_out;

    float* partial = (float*)d_ws;            // 4096 floats
    int*   cnt     = (int*)(partial + 4096);  // 4096 ints

    level0_kernel<<<512, 256, 0, stream>>>(gt, dense, partial, cnt);
    levels_kernel<<<1, 512, 0, stream>>>(partial, cnt, l1, l2, l3, l4, out);
}